// Round 4
// baseline (223.101 us; speedup 1.0000x reference)
//
#include <hip/hip_runtime.h>

#define NTOK 1024
#define DDIM 128

typedef _Float16 f16;
typedef _Float16 f16x4 __attribute__((ext_vector_type(4)));
typedef _Float16 f16x8 __attribute__((ext_vector_type(8)));
typedef float f32x16 __attribute__((ext_vector_type(16)));
typedef unsigned int uint;

#define AS1 __attribute__((address_space(1)))
#define AS3 __attribute__((address_space(3)))

// ---------------- fused prepass ---------------------------------------------
// blocks [0,512):  x -> xhn (normalized f16) + xhT (unscaled f16 transpose)
// blocks [512,768): betaT[m][i] = beta[i][m]
__global__ __launch_bounds__(256) void prep_fused(
    const float* __restrict__ x, const float* __restrict__ beta,
    f16* __restrict__ xhn, f16* __restrict__ xhT, float* __restrict__ betaT) {
  __shared__ __align__(16) char psm[128 * 132 * 2];
  int bx = blockIdx.x;
  int t = threadIdx.x;
  if (bx < 512) {
    f16* sT = (f16*)psm;  // [128][132]
    int bc = bx & 63;
    int nt = bx >> 6;
    int n0 = nt * 128;
    const float4* xv = (const float4*)(x + ((size_t)bc * NTOK + n0) * DDIM);
#pragma unroll
    for (int k = 0; k < 16; ++k) {
      int idx = t + 256 * k;
      int row = idx >> 5;
      int c4 = idx & 31;
      float4 v = xv[(size_t)row * 32 + c4];
      float ss = v.x * v.x + v.y * v.y + v.z * v.z + v.w * v.w;
      ss += __shfl_xor(ss, 1);
      ss += __shfl_xor(ss, 2);
      ss += __shfl_xor(ss, 4);
      ss += __shfl_xor(ss, 8);
      ss += __shfl_xor(ss, 16);
      float rn = (ss > 0.f) ? rsqrtf(ss) : 0.f;
      f16x4 hn = {(f16)(v.x * rn), (f16)(v.y * rn), (f16)(v.z * rn),
                  (f16)(v.w * rn)};
      *(f16x4*)(xhn + ((size_t)bc * NTOK + n0 + row) * DDIM + c4 * 4) = hn;
      f16x4 hv = {(f16)v.x, (f16)v.y, (f16)v.z, (f16)v.w};
      *(f16x4*)(sT + row * 132 + c4 * 4) = hv;
    }
    __syncthreads();
    int dr = t >> 1;
    int half = t & 1;
    f16* dst = xhT + ((size_t)bc * DDIM + dr) * NTOK + n0 + 64 * half;
#pragma unroll
    for (int s = 0; s < 8; ++s) {
      f16x8 tmp;
#pragma unroll
      for (int j = 0; j < 8; ++j)
        tmp[j] = sT[(64 * half + s * 8 + j) * 132 + dr];
      *(f16x8*)(dst + s * 8) = tmp;
    }
  } else {
    float(*s)[65] = (float(*)[65])psm;
    int bb = bx - 512;
    int bi = bb & 15;
    int bj = bb >> 4;
    int r = t >> 4;
    int c4 = (t & 15) * 4;
#pragma unroll
    for (int rr = 0; rr < 64; rr += 16) {
      float4 v = *(const float4*)(beta + (size_t)(bi * 64 + r + rr) * NTOK +
                                  bj * 64 + c4);
      s[r + rr][c4] = v.x;
      s[r + rr][c4 + 1] = v.y;
      s[r + rr][c4 + 2] = v.z;
      s[r + rr][c4 + 3] = v.w;
    }
    __syncthreads();
#pragma unroll
    for (int rr = 0; rr < 64; rr += 16) {
      int m = r + rr;
      float4 v = {s[c4][m], s[c4 + 1][m], s[c4 + 2][m], s[c4 + 3][m]};
      *(float4*)(betaT + (size_t)(bj * 64 + m) * NTOK + bi * 64 + c4) = v;
    }
  }
}

// ---------------- main ------------------------------------------------------
// 512 blocks (all co-resident): bc = bx&63, q-pair = (bx>>6)*128. Each block
// processes TWO 64-row q-subtiles against each staged 64-row m-tile, so one
// 32KB DMA feeds 2x the MFMA of the R3 version. Beta loads issued BEFORE the
// prefetch DMA so their vmcnt wait doesn't drain it.
__global__ __launch_bounds__(256, 2) void cos_att_main(
    const f16* __restrict__ xhn, const f16* __restrict__ xhT,
    const float* __restrict__ betaT, float* __restrict__ out) {
  __shared__ __align__(16) char smem[65536];  // dbuf: 2 x (sXm 16K + sXmT 16K)
  int bx = blockIdx.x;
  int bc = bx & 63;
  int qp = bx >> 6;  // 0..7
  int q0 = qp * 128;

  int t = threadIdx.x;
  int lane = t & 63;
  int w = t >> 6;
  int l31 = lane & 31;
  int hi = lane >> 5;
  int i_str = (w >> 1) * 32;  // 0/32 within each 64-row subtile
  int m_str = (w & 1) * 32;

  // Xq B-frags for both subtiles, resident in registers
  f16x8 xqA[8], xqB[8];
  {
    const f16* baseA =
        xhn + ((size_t)bc * NTOK + q0 + i_str + l31) * DDIM + hi * 8;
    const f16* baseB = baseA + (size_t)64 * DDIM;
#pragma unroll
    for (int kk = 0; kk < 8; ++kk) {
      xqA[kk] = *(const f16x8*)(baseA + kk * 16);
      xqB[kk] = *(const f16x8*)(baseB + kk * 16);
    }
  }

  auto stage = [&](int mi, int b) {
    int m0 = mi * 64;
    char* ldsm = smem + b * 32768;
    char* ldst = ldsm + 16384;
    {  // sXm: 64 rows x 256B, LDS[r][c'] = G[r][(c'&8)|((c'&7)^(r&7))]
      int lr = lane >> 4;
      int cp = lane & 15;
      const f16* gb = xhn + ((size_t)bc * NTOK + m0) * DDIM;
#pragma unroll
      for (int j = 0; j < 4; ++j) {
        int r = 16 * w + 4 * j + lr;
        int g = (cp & 8) | ((cp & 7) ^ (r & 7));
        const f16* gp = gb + (size_t)r * DDIM + g * 8;
        __builtin_amdgcn_global_load_lds(
            (const AS1 uint*)gp, (AS3 uint*)(ldsm + (16 * w + 4 * j) * 256),
            16, 0, 0);
      }
    }
    {  // sXmT: 128 rows x 128B, LDS[d][c'] = G[d][c'^(d&7)]
      int lr = lane >> 3;
      int cp = lane & 7;
      const f16* gb = xhT + (size_t)bc * DDIM * NTOK + m0;
#pragma unroll
      for (int j = 0; j < 4; ++j) {
        int d = 32 * w + 8 * j + lr;
        int g = cp ^ (d & 7);
        const f16* gp = gb + (size_t)d * NTOK + g * 8;
        __builtin_amdgcn_global_load_lds(
            (const AS1 uint*)gp, (AS3 uint*)(ldst + (32 * w + 8 * j) * 128),
            16, 0, 0);
      }
    }
  };

  stage(0, 0);

  f32x16 o[8];
#pragma unroll
  for (int dt = 0; dt < 8; ++dt)
#pragma unroll
    for (int z = 0; z < 16; ++z) o[dt][z] = 0.f;

  for (int mi = 0; mi < 16; ++mi) {
    int b = mi & 1;
    int m0 = mi * 64;
    __syncthreads();  // buf[b] DMA drained; prev reads of buf[1-b] done

    // beta loads FIRST (oldest vmem) so waiting on them leaves DMA in flight
    float bvA[16], bvB[16];
    {
      const float* bbA =
          betaT + (size_t)(m0 + m_str) * NTOK + q0 + i_str + l31;
      const float* bbB = bbA + 64;
#pragma unroll
      for (int r = 0; r < 16; ++r) {
        int rowl = (r & 3) + 8 * (r >> 2) + 4 * hi;
        bvA[r] = bbA[(size_t)rowl * NTOK];
        bvB[r] = bbB[(size_t)rowl * NTOK];
      }
    }
    if (mi < 15) stage(mi + 1, 1 - b);

    const char* ldsm = smem + b * 32768;
    const char* ldst = ldsm + 16384;

    // GEMM1 (joint): S^T = Xm . Xq^T for both subtiles, shared A-frag
    f32x16 s0, s1;
#pragma unroll
    for (int z = 0; z < 16; ++z) {
      s0[z] = 0.f;
      s1[z] = 0.f;
    }
    {
      int rA = m_str + l31;
      const char* rowA = ldsm + rA * 256;
      int rx = rA & 7;
#pragma unroll
      for (int kk = 0; kk < 8; ++kk) {
        int g = 2 * kk + hi;
        int cp = (g & 8) | ((g & 7) ^ rx);
        f16x8 a = *(const f16x8*)(rowA + cp * 16);
        s0 = __builtin_amdgcn_mfma_f32_32x32x16_f16(a, xqA[kk], s0, 0, 0, 0);
        s1 = __builtin_amdgcn_mfma_f32_32x32x16_f16(a, xqB[kk], s1, 0, 0, 0);
      }
    }

#pragma unroll
    for (int sub = 0; sub < 2; ++sub) {
      const f32x16& s = sub ? s1 : s0;
      const float* bv = sub ? bvB : bvA;
      // P = sigmoid(beta * cos), packed to f16x2 dwords
      float pk[8];
#pragma unroll
      for (int rp = 0; rp < 8; ++rp) {
        float t0 = bv[2 * rp] * s[2 * rp];
        float t1 = bv[2 * rp + 1] * s[2 * rp + 1];
        float e0 = __builtin_amdgcn_exp2f(-1.44269504f * t0);
        float e1 = __builtin_amdgcn_exp2f(-1.44269504f * t1);
        float p0 = __builtin_amdgcn_rcpf(1.0f + e0);
        float p1 = __builtin_amdgcn_rcpf(1.0f + e1);
        pk[rp] = __builtin_bit_cast(float, __builtin_amdgcn_cvt_pkrtz(p0, p1));
      }
      float qk[8];
#pragma unroll
      for (int rp = 0; rp < 8; ++rp) qk[rp] = __shfl_xor(pk[rp], 32);
      union {
        float f[4];
        f16x8 h;
      } bt0, bt1;
      bt0.f[0] = hi ? qk[2] : pk[0];
      bt0.f[1] = hi ? qk[3] : pk[1];
      bt0.f[2] = hi ? pk[2] : qk[0];
      bt0.f[3] = hi ? pk[3] : qk[1];
      bt1.f[0] = hi ? qk[6] : pk[4];
      bt1.f[1] = hi ? qk[7] : pk[5];
      bt1.f[2] = hi ? pk[6] : qk[4];
      bt1.f[3] = hi ? pk[7] : qk[5];

      // GEMM2: O^T[d][i] += XmT . P, K=32
#pragma unroll
      for (int dt = 0; dt < 4; ++dt) {
        int d = dt * 32 + l31;
        const char* rowT = ldst + d * 128;
        int dx = d & 7;
        int g0 = (m_str >> 3) + hi;
        f16x8 a0 = *(const f16x8*)(rowT + (g0 ^ dx) * 16);
        f16x8 a1 = *(const f16x8*)(rowT + ((g0 + 2) ^ dx) * 16);
        o[sub * 4 + dt] =
            __builtin_amdgcn_mfma_f32_32x32x16_f16(a0, bt0.h, o[sub * 4 + dt], 0, 0, 0);
        o[sub * 4 + dt] =
            __builtin_amdgcn_mfma_f32_32x32x16_f16(a1, bt1.h, o[sub * 4 + dt], 0, 0, 0);
      }
    }
  }

  // epilogue: per subtile, pair-reduce (m_str 0+32) + transpose via LDS
  float* sO = (float*)smem;  // [64][132]
#pragma unroll
  for (int sub = 0; sub < 2; ++sub) {
    __syncthreads();
    if ((w & 1) == 0) {
#pragma unroll
      for (int dt = 0; dt < 4; ++dt)
#pragma unroll
        for (int r = 0; r < 16; ++r) {
          int rowl = (r & 3) + 8 * (r >> 2) + 4 * hi;
          sO[(i_str + l31) * 132 + dt * 32 + rowl] = o[sub * 4 + dt][r];
        }
    }
    __syncthreads();
    if (w & 1) {
#pragma unroll
      for (int dt = 0; dt < 4; ++dt)
#pragma unroll
        for (int r = 0; r < 16; ++r) {
          int rowl = (r & 3) + 8 * (r >> 2) + 4 * hi;
          sO[(i_str + l31) * 132 + dt * 32 + rowl] += o[sub * 4 + dt][r];
        }
    }
    __syncthreads();
    float* og = out + ((size_t)bc * NTOK + q0 + sub * 64) * DDIM;
#pragma unroll
    for (int k = 0; k < 8; ++k) {
      int idx = t + 256 * k;
      int row = idx >> 5;
      int c4 = idx & 31;
      *(float4*)(og + (size_t)row * DDIM + c4 * 4) =
          *(const float4*)(sO + row * 132 + c4 * 4);
    }
  }
}

extern "C" void kernel_launch(void* const* d_in, const int* in_sizes, int n_in,
                              void* d_out, int out_size, void* d_ws,
                              size_t ws_size, hipStream_t stream) {
  const float* x = (const float*)d_in[0];
  const float* beta = (const float*)d_in[1];
  float* out = (float*)d_out;

  char* ws = (char*)d_ws;
  f16* xhn = (f16*)ws;                       // 16 MB
  f16* xhT = (f16*)(ws + (16 << 20));        // 16 MB
  float* betaT = (float*)(ws + (32 << 20));  // 4 MB

  prep_fused<<<768, 256, 0, stream>>>(x, beta, xhn, xhT, betaT);
  cos_att_main<<<512, 256, 0, stream>>>(xhn, xhT, betaT, out);
}

// Round 6
// 137.277 us; speedup vs baseline: 1.6252x; 1.6252x over previous
//
#include <hip/hip_runtime.h>

#define NTOK 1024
#define DDIM 128

typedef _Float16 f16;
typedef _Float16 f16x2v __attribute__((ext_vector_type(2)));
typedef _Float16 f16x4 __attribute__((ext_vector_type(4)));
typedef _Float16 f16x8 __attribute__((ext_vector_type(8)));
typedef float f32x16 __attribute__((ext_vector_type(16)));
typedef unsigned int uint;
typedef long i64;

union PFrag {
  float f[4];
  f16x8 h;
};

#define AS1 __attribute__((address_space(1)))
#define AS3 __attribute__((address_space(3)))
#define NLOG2E -1.44269504f

// ---------------- fused prepass ---------------------------------------------
// blocks [0,512):  x -> x8n (normalized fp8-e4m3) + xhT (unscaled f16 transp)
// blocks [512,768): beta -> betaTp: f16 pairs [m>>1][i][2], pre-scaled -log2e
__global__ __launch_bounds__(256) void prep_fused(
    const float* __restrict__ x, const float* __restrict__ beta,
    unsigned char* __restrict__ x8n, f16* __restrict__ xhT,
    uint* __restrict__ betaTp) {
  __shared__ __align__(16) char psm[128 * 132 * 2];
  int bx = blockIdx.x;
  int t = threadIdx.x;
  if (bx < 512) {
    f16* sT = (f16*)psm;  // [128][132]
    int bc = bx & 63;
    int nt = bx >> 6;
    int n0 = nt * 128;
    const float4* xv = (const float4*)(x + ((size_t)bc * NTOK + n0) * DDIM);
#pragma unroll
    for (int k = 0; k < 16; ++k) {
      int idx = t + 256 * k;
      int row = idx >> 5;
      int c4 = idx & 31;
      float4 v = xv[(size_t)row * 32 + c4];
      float ss = v.x * v.x + v.y * v.y + v.z * v.z + v.w * v.w;
      ss += __shfl_xor(ss, 1);
      ss += __shfl_xor(ss, 2);
      ss += __shfl_xor(ss, 4);
      ss += __shfl_xor(ss, 8);
      ss += __shfl_xor(ss, 16);
      float rn = (ss > 0.f) ? rsqrtf(ss) : 0.f;
      int p01 = __builtin_amdgcn_cvt_pk_fp8_f32(v.x * rn, v.y * rn, 0, false);
      int p03 = __builtin_amdgcn_cvt_pk_fp8_f32(v.z * rn, v.w * rn, p01, true);
      *(int*)(x8n + ((size_t)bc * NTOK + n0 + row) * DDIM + c4 * 4) = p03;
      f16x4 hv = {(f16)v.x, (f16)v.y, (f16)v.z, (f16)v.w};
      *(f16x4*)(sT + row * 132 + c4 * 4) = hv;
    }
    __syncthreads();
    int dr = t >> 1;
    int half = t & 1;
    f16* dst = xhT + ((size_t)bc * DDIM + dr) * NTOK + n0 + 64 * half;
#pragma unroll
    for (int s = 0; s < 8; ++s) {
      f16x8 tmp;
#pragma unroll
      for (int j = 0; j < 8; ++j)
        tmp[j] = sT[(64 * half + s * 8 + j) * 132 + dr];
      *(f16x8*)(dst + s * 8) = tmp;
    }
  } else {
    float(*s)[65] = (float(*)[65])psm;
    int bb = bx - 512;
    int bi = bb & 15;   // i tile
    int bj = bb >> 4;   // m tile
    int r = t >> 4;
    int c4 = (t & 15) * 4;
#pragma unroll
    for (int rr = 0; rr < 64; rr += 16) {
      float4 v = *(const float4*)(beta + (size_t)(bi * 64 + r + rr) * NTOK +
                                  bj * 64 + c4);
      s[r + rr][c4] = v.x;
      s[r + rr][c4 + 1] = v.y;
      s[r + rr][c4 + 2] = v.z;
      s[r + rr][c4 + 3] = v.w;
    }
    __syncthreads();
    int il = t & 63;
#pragma unroll
    for (int rr = 0; rr < 8; ++rr) {
      int m2 = (t >> 6) + 4 * rr;  // 0..31
      float b0 = s[il][2 * m2] * NLOG2E;
      float b1 = s[il][2 * m2 + 1] * NLOG2E;
      uint u = __builtin_bit_cast(uint, __builtin_amdgcn_cvt_pkrtz(b0, b1));
      betaTp[(size_t)(bj * 32 + m2) * NTOK + bi * 64 + il] = u;
    }
  }
}

// ---------------- main ------------------------------------------------------
// 512 blocks, 2/CU. Two 64-row q-subtiles per block share every staged m-tile
// and every LDS A-fragment (GEMM1: fp8 Xm rows; GEMM2: f16 XmT rows).
__global__ __launch_bounds__(256, 2) void cos_att_main(
    const unsigned char* __restrict__ x8n, const f16* __restrict__ xhT,
    const uint* __restrict__ betaTp, float* __restrict__ out) {
  __shared__ __align__(16) char smem[49152];  // dbuf: 2 x (sXm8 8K + sXmT 16K)
  int bx = blockIdx.x;
  int bc = bx & 63;
  int qp = bx >> 6;  // 0..7
  int q0 = qp * 128;

  int t = threadIdx.x;
  int lane = t & 63;
  int w = t >> 6;
  int l31 = lane & 31;
  int hi = lane >> 5;
  int i_str = (w >> 1) * 32;
  int m_str = (w & 1) * 32;

  // Xq B-frags (fp8) for both subtiles, resident in registers (16+16 VGPRs)
  i64 xqA8[8], xqB8[8];
  {
    const unsigned char* baseA =
        x8n + ((size_t)bc * NTOK + q0 + i_str + l31) * DDIM + hi * 8;
    const unsigned char* baseB = baseA + (size_t)64 * DDIM;
#pragma unroll
    for (int kk = 0; kk < 8; ++kk) {
      xqA8[kk] = *(const i64*)(baseA + kk * 16);
      xqB8[kk] = *(const i64*)(baseB + kk * 16);
    }
  }

  auto stage = [&](int mi, int b) {
    int m0 = mi * 64;
    char* ldsm8 = smem + b * 24576;
    char* ldst = ldsm8 + 8192;
    {  // sXm8: 64 rows x 128B fp8, 16B-chunk XOR by (r&7)
      const unsigned char* gb8 = x8n + ((size_t)bc * NTOK + m0) * DDIM;
#pragma unroll
      for (int j = 0; j < 2; ++j) {
        int u = t + 256 * j;
        int r = u >> 3;
        int cp = u & 7;
        const unsigned char* gp = gb8 + (size_t)r * DDIM + ((cp ^ (r & 7)) * 16);
        __builtin_amdgcn_global_load_lds((const AS1 uint*)gp,
                                         (AS3 uint*)(ldsm8 + u * 16), 16, 0, 0);
      }
    }
    {  // sXmT: 128 rows x 128B f16, 16B-chunk XOR by (d&7)
      int lr = lane >> 3;
      int cp = lane & 7;
      const f16* gb = xhT + (size_t)bc * DDIM * NTOK + m0;
#pragma unroll
      for (int j = 0; j < 4; ++j) {
        int d = 32 * w + 8 * j + lr;
        int g = cp ^ (d & 7);
        const f16* gp = gb + (size_t)d * NTOK + g * 8;
        __builtin_amdgcn_global_load_lds(
            (const AS1 uint*)gp, (AS3 uint*)(ldst + (32 * w + 8 * j) * 128),
            16, 0, 0);
      }
    }
  };

  stage(0, 0);

  f32x16 o[8];
#pragma unroll
  for (int dt = 0; dt < 8; ++dt)
#pragma unroll
    for (int z = 0; z < 16; ++z) o[dt][z] = 0.f;

  for (int mi = 0; mi < 16; ++mi) {
    int b = mi & 1;
    int m0 = mi * 64;
    __syncthreads();  // buf[b] DMA drained; prev reads of buf[1-b] done

    // beta loads FIRST (oldest vmem): f16 pairs, 8 dwords per subtile
    uint bvpA[8], bvpB[8];
    {
      const uint* bbase =
          betaTp + (size_t)((m0 + m_str) >> 1) * NTOK + q0 + i_str + l31;
#pragma unroll
      for (int rp = 0; rp < 8; ++rp) {
        int m2l = (rp & 1) + 4 * (rp >> 1) + 2 * hi;
        bvpA[rp] = bbase[(size_t)m2l * NTOK];
        bvpB[rp] = bbase[(size_t)m2l * NTOK + 64];
      }
    }
    if (mi < 15) stage(mi + 1, 1 - b);

    const char* ldsm8 = smem + b * 24576;
    const char* ldst = ldsm8 + 8192;

    // GEMM1 (fp8): S^T = Xm . Xq^T for both subtiles, shared A-frag (b64)
    f32x16 s0, s1;
#pragma unroll
    for (int z = 0; z < 16; ++z) {
      s0[z] = 0.f;
      s1[z] = 0.f;
    }
    {
      int rA = m_str + l31;
      const char* rowA = ldsm8 + rA * 128;
      int rx = rA & 7;
#pragma unroll
      for (int kk = 0; kk < 8; ++kk) {
        i64 a = *(const i64*)(rowA + ((kk ^ rx) * 16) + hi * 8);
        s0 = __builtin_amdgcn_mfma_f32_32x32x16_fp8_fp8(a, xqA8[kk], s0, 0, 0, 0);
        s1 = __builtin_amdgcn_mfma_f32_32x32x16_fp8_fp8(a, xqB8[kk], s1, 0, 0, 0);
      }
    }

    // sigmoid for BOTH subtiles (s0/s1 die here), P packed to f16x2 dwords
    PFrag btA0, btA1, btB0, btB1;
#pragma unroll
    for (int sub = 0; sub < 2; ++sub) {
      const f32x16& s = sub ? s1 : s0;
      const uint* bvp = sub ? bvpB : bvpA;
      float pk[8];
#pragma unroll
      for (int rp = 0; rp < 8; ++rp) {
        f16x2v bh = __builtin_bit_cast(f16x2v, bvp[rp]);
        // betaTp pre-scaled by -log2(e): P = rcp(1 + exp2(b'*cos))
        float e0 = __builtin_amdgcn_exp2f((float)bh[0] * s[2 * rp]);
        float e1 = __builtin_amdgcn_exp2f((float)bh[1] * s[2 * rp + 1]);
        float p0 = __builtin_amdgcn_rcpf(1.0f + e0);
        float p1 = __builtin_amdgcn_rcpf(1.0f + e1);
        pk[rp] = __builtin_bit_cast(float, __builtin_amdgcn_cvt_pkrtz(p0, p1));
      }
      float qk[8];
#pragma unroll
      for (int rp = 0; rp < 8; ++rp) qk[rp] = __shfl_xor(pk[rp], 32);
      PFrag b0, b1;
      b0.f[0] = hi ? qk[2] : pk[0];
      b0.f[1] = hi ? qk[3] : pk[1];
      b0.f[2] = hi ? pk[2] : qk[0];
      b0.f[3] = hi ? pk[3] : qk[1];
      b1.f[0] = hi ? qk[6] : pk[4];
      b1.f[1] = hi ? qk[7] : pk[5];
      b1.f[2] = hi ? pk[6] : qk[4];
      b1.f[3] = hi ? pk[7] : qk[5];
      if (sub == 0) {
        btA0 = b0;
        btA1 = b1;
      } else {
        btB0 = b0;
        btB1 = b1;
      }
    }

    // GEMM2 (f16): O^T[d][i] += XmT . P; A-frags read ONCE, shared across subs
#pragma unroll
    for (int dt = 0; dt < 4; ++dt) {
      int d = dt * 32 + l31;
      const char* rowT = ldst + d * 128;
      int dx = d & 7;
      int g0 = (m_str >> 3) + hi;
      f16x8 a0 = *(const f16x8*)(rowT + (g0 ^ dx) * 16);
      f16x8 a1 = *(const f16x8*)(rowT + ((g0 + 2) ^ dx) * 16);
      o[dt] = __builtin_amdgcn_mfma_f32_32x32x16_f16(a0, btA0.h, o[dt], 0, 0, 0);
      o[dt] = __builtin_amdgcn_mfma_f32_32x32x16_f16(a1, btA1.h, o[dt], 0, 0, 0);
      o[4 + dt] =
          __builtin_amdgcn_mfma_f32_32x32x16_f16(a0, btB0.h, o[4 + dt], 0, 0, 0);
      o[4 + dt] =
          __builtin_amdgcn_mfma_f32_32x32x16_f16(a1, btB1.h, o[4 + dt], 0, 0, 0);
    }
  }

  // epilogue: per subtile, pair-reduce (m_str 0+32) + transpose via LDS
  float* sO = (float*)smem;  // [64][132] = 33792 B < 49152
#pragma unroll
  for (int sub = 0; sub < 2; ++sub) {
    __syncthreads();
    if ((w & 1) == 0) {
#pragma unroll
      for (int dt = 0; dt < 4; ++dt)
#pragma unroll
        for (int r = 0; r < 16; ++r) {
          int rowl = (r & 3) + 8 * (r >> 2) + 4 * hi;
          sO[(i_str + l31) * 132 + dt * 32 + rowl] = o[sub * 4 + dt][r];
        }
    }
    __syncthreads();
    if (w & 1) {
#pragma unroll
      for (int dt = 0; dt < 4; ++dt)
#pragma unroll
        for (int r = 0; r < 16; ++r) {
          int rowl = (r & 3) + 8 * (r >> 2) + 4 * hi;
          sO[(i_str + l31) * 132 + dt * 32 + rowl] += o[sub * 4 + dt][r];
        }
    }
    __syncthreads();
    float* og = out + ((size_t)bc * NTOK + q0 + sub * 64) * DDIM;
#pragma unroll
    for (int k = 0; k < 8; ++k) {
      int idx = t + 256 * k;
      int row = idx >> 5;
      int c4 = idx & 31;
      *(float4*)(og + (size_t)row * DDIM + c4 * 4) =
          *(const float4*)(sO + row * 132 + c4 * 4);
    }
  }
}

extern "C" void kernel_launch(void* const* d_in, const int* in_sizes, int n_in,
                              void* d_out, int out_size, void* d_ws,
                              size_t ws_size, hipStream_t stream) {
  const float* x = (const float*)d_in[0];
  const float* beta = (const float*)d_in[1];
  float* out = (float*)d_out;

  char* ws = (char*)d_ws;
  unsigned char* x8n = (unsigned char*)ws;  // 8 MB
  f16* xhT = (f16*)(ws + (8 << 20));        // 16 MB
  uint* betaTp = (uint*)(ws + (24 << 20));  // 2 MB

  prep_fused<<<768, 256, 0, stream>>>(x, beta, x8n, xhT, betaTp);
  cos_att_main<<<512, 256, 0, stream>>>(x8n, xhT, betaTp, out);
}